// Round 4
// baseline (61.126 us; speedup 1.0000x reference)
//
#include <hip/hip_runtime.h>
#include <math.h>

#define NVIEW 3
#define HLOW 256
#define WLOW 256
#define NPIX (HLOW * WLOW)
#define NS 64
#define VOLN 128
#define IMGH 512
#define IMGW 512
#define BLK 256
#define RAYS_PER_BLOCK 128                       // 2 threads per ray (even/odd samples)
#define BLOCKS_PER_VIEW (NPIX / RAYS_PER_BLOCK)  // 512

// 2 threads per ray: lane pair (2r, 2r+1) takes even/odd depth samples (32 each),
// merged by __shfl_xor at the end. Doubles waves/CU vs 1-thread-per-ray while
// keeping a 32-sample unrolled loop for memory-level parallelism.
// Grid coords are affine in z (precomputed per ray); the outside-sphere test is
// a precomputed z-interval (r^2(z) quadratic); border clamp handled by basing the
// cell at min(i,126) with frac in [0,1] (exact at borders) -> fixed +128/+16384
// neighbor offsets, no per-sample selects.
__global__ __launch_bounds__(BLK) void raymarch_kernel(
    const float* __restrict__ intrs,    // [3,3,3]
    const float* __restrict__ c2ws,     // [3,4,4]
    const float* __restrict__ nearfars, // [3,2]
    const float* __restrict__ vol,      // [128,128,128] (D,H,W)
    float* __restrict__ depth_low,      // [3,256,256]
    float* __restrict__ partials)       // [3*512][3]
{
    const int view   = blockIdx.x >> 9;
    const int rayblk = blockIdx.x & 511;
    const int t      = threadIdx.x;
    const int rloc   = t >> 1;
    const int par    = t & 1;
    const int ray    = rayblk * RAYS_PER_BLOCK + rloc;
    const int row    = ray >> 8;
    const int col    = ray & 255;

    // pixel grid: linspace(0, 511, 256)
    const float px = 511.0f * (float)col * (1.0f / 255.0f);
    const float py = 511.0f * (float)row * (1.0f / 255.0f);

    // analytic 3x3 inverse of intr
    const float* K = intrs + view * 9;
    const float a = K[0], b = K[1], c = K[2];
    const float d = K[3], e = K[4], f = K[5];
    const float g = K[6], h = K[7], i9 = K[8];
    const float det = a * (e * i9 - f * h) - b * (d * i9 - f * g) + c * (d * h - e * g);
    const float id = 1.0f / det;
    const float m00 = (e * i9 - f * h) * id, m01 = -(b * i9 - c * h) * id, m02 = (b * f - c * e) * id;
    const float m10 = -(d * i9 - f * g) * id, m11 = (a * i9 - c * g) * id, m12 = -(a * f - c * d) * id;
    const float m20 = (d * h - e * g) * id, m21 = -(a * h - b * g) * id, m22 = (a * e - b * d) * id;

    const float cx = m00 * px + m01 * py + m02;
    const float cy = m10 * px + m11 * py + m12;
    const float cz = m20 * px + m21 * py + m22;
    const float inr = rsqrtf(cx * cx + cy * cy + cz * cz);
    const float ncx = cx * inr, ncy = cy * inr, ncz = cz * inr;

    const float* M = c2ws + view * 16;
    const float dx = M[0] * ncx + M[1] * ncy + M[2] * ncz;
    const float dy = M[4] * ncx + M[5] * ncy + M[6] * ncz;
    const float dz = M[8] * ncx + M[9] * ncy + M[10] * ncz;
    const float tx = M[3], ty = M[7], tz = M[11];

    const float nearv = nearfars[view * 2 + 0];
    const float farv  = nearfars[view * 2 + 1];
    const float zstep = (farv - nearv) * (1.0f / 63.0f);

    // grid coords affine in z: g = (w + 1) * 63.5, w = t + d*z
    const float gx0 = (tx + 1.0f) * 63.5f, gxs = dx * 63.5f;
    const float gy0 = (ty + 1.0f) * 63.5f, gys = dy * 63.5f;
    const float gz0 = (tz + 1.0f) * 63.5f, gzs = dz * 63.5f;

    // outside-sphere interval: r^2(z) = z^2 + 2 bq z + cq  (|d| = 1)
    const float bq = tx * dx + ty * dy + tz * dz;
    const float cq = tx * tx + ty * ty + tz * tz;
    const float disc = bq * bq - (cq - 1.0f);
    float zlo, zhi;
    if (disc >= 0.0f) {
        const float r = sqrtf(disc);
        zlo = -bq - r;
        zhi = -bq + r;
    } else {            // ray never enters the unit sphere: always outside
        zlo = 3.4e38f;
        zhi = 0.0f;
    }

    const float z0p = nearv + zstep * (float)par; // this thread's first sample
    const float zs2 = zstep * 2.0f;               // stride 2 samples

    float lsum = 0.0f, zacc = 0.0f;
    float d6 = 0.0f, dout = 0.0f, cnt = 0.0f;

    #pragma unroll 8
    for (int i = 0; i < NS / 2; ++i) {
        const float z = fmaf(zs2, (float)i, z0p);

        float gx = fmaf(gxs, z, gx0);
        float gy = fmaf(gys, z, gy0);
        float gz = fmaf(gzs, z, gz0);
        gx = fminf(fmaxf(gx, 0.0f), 127.0f);
        gy = fminf(fmaxf(gy, 0.0f), 127.0f);
        gz = fminf(fmaxf(gz, 0.0f), 127.0f);

        // cell base clamped to 126: frac in [0,1], exact at the border
        const int xb = min((int)gx, VOLN - 2);
        const int yb = min((int)gy, VOLN - 2);
        const int zb = min((int)gz, VOLN - 2);
        const float fx = gx - (float)xb;
        const float fy = gy - (float)yb;
        const float fz = gz - (float)zb;

        const unsigned off = ((unsigned)zb << 14) + ((unsigned)yb << 7) + (unsigned)xb;
        const float* p0 = vol + off;
        const float* p1 = p0 + (VOLN * VOLN);
        const float2 v00 = *reinterpret_cast<const float2*>(p0);
        const float2 v01 = *reinterpret_cast<const float2*>(p0 + VOLN);
        const float2 v10 = *reinterpret_cast<const float2*>(p1);
        const float2 v11 = *reinterpret_cast<const float2*>(p1 + VOLN);

        const float c00 = fmaf(fx, v00.y - v00.x, v00.x);
        const float c01 = fmaf(fx, v01.y - v01.x, v01.x);
        const float c10 = fmaf(fx, v10.y - v10.x, v10.x);
        const float c11 = fmaf(fx, v11.y - v11.x, v11.x);
        const float c0 = fmaf(fy, c01 - c00, c00);
        const float c1 = fmaf(fy, c11 - c10, c10);
        const float dens = fmaf(fz, c1 - c0, c0);

        const float w = __expf(dens);
        lsum += w;
        zacc = fmaf(z, w, zacc);

        if (i < 3) d6 += dens;                  // s = 2i+par < 6  <=>  i < 3
        const bool o = (z < zlo) || (z > zhi);
        dout += o ? dens : 0.0f;
        cnt  += o ? 1.0f : 0.0f;
    }

    // merge the even/odd halves within the lane pair
    lsum += __shfl_xor(lsum, 1);
    zacc += __shfl_xor(zacc, 1);
    if (par == 0)
        depth_low[view * NPIX + ray] = (zacc / lsum) * ncz;

    // deterministic block tree-reduction of the three occ partial sums
    __shared__ float s0[BLK], s1[BLK], s2[BLK];
    s0[t] = d6; s1[t] = dout; s2[t] = cnt;
    __syncthreads();
    for (int off = BLK / 2; off > 0; off >>= 1) {
        if (t < off) {
            s0[t] += s0[t + off];
            s1[t] += s1[t + off];
            s2[t] += s2[t + off];
        }
        __syncthreads();
    }
    if (t == 0) {
        partials[blockIdx.x * 3 + 0] = s0[0];
        partials[blockIdx.x * 3 + 1] = s1[0];
        partials[blockIdx.x * 3 + 2] = s2[0];
    }
}

// One block per view: reduce the 512 block-partials, write occ scalar.
__global__ __launch_bounds__(256) void reduce_occ_kernel(
    const float* __restrict__ partials, float* __restrict__ out_occ)
{
    const int view = blockIdx.x;
    const int t = threadIdx.x;
    __shared__ float s0[256], s1[256], s2[256];
    float a0 = 0.0f, a1 = 0.0f, a2 = 0.0f;
    for (int k = t; k < BLOCKS_PER_VIEW; k += 256) {
        const int bi = view * BLOCKS_PER_VIEW + k;
        a0 += partials[bi * 3 + 0];
        a1 += partials[bi * 3 + 1];
        a2 += partials[bi * 3 + 2];
    }
    s0[t] = a0; s1[t] = a1; s2[t] = a2;
    __syncthreads();
    for (int off = 128; off > 0; off >>= 1) {
        if (t < off) {
            s0[t] += s0[t + off];
            s1[t] += s1[t + off];
            s2[t] += s2[t + off];
        }
        __syncthreads();
    }
    if (t == 0) {
        out_occ[view] = s0[0] * (1.0f / (float)(NPIX * 6))
                      + s1[0] / (s2[0] + 1e-10f);
    }
}

// 256x256 -> 512x512 bilinear, jax.image.resize semantics:
// src = (i + 0.5) * 0.5 - 0.5; edge renormalization == index clamp.
__global__ __launch_bounds__(BLK) void upsample_kernel(
    const float* __restrict__ low, float* __restrict__ out)
{
    const int idx = blockIdx.x * BLK + threadIdx.x;
    const int view = idx / (IMGH * IMGW);
    const int rem = idx - view * (IMGH * IMGW);
    const int r = rem >> 9;
    const int cc = rem & 511;

    const float sy = (float)r * 0.5f - 0.25f;
    const float sx = (float)cc * 0.5f - 0.25f;
    const float y0f = floorf(sy), x0f = floorf(sx);
    const float wy = sy - y0f, wx = sx - x0f;
    const int y0 = (int)y0f, x0 = (int)x0f;
    const int y0c = max(y0, 0), y1c = min(y0 + 1, HLOW - 1);
    const int x0c = max(x0, 0), x1c = min(x0 + 1, WLOW - 1);

    const float* src = low + view * NPIX;
    const float v00 = src[y0c * WLOW + x0c];
    const float v01 = src[y0c * WLOW + x1c];
    const float v10 = src[y1c * WLOW + x0c];
    const float v11 = src[y1c * WLOW + x1c];

    const float top = v00 * (1.0f - wx) + v01 * wx;
    const float bot = v10 * (1.0f - wx) + v11 * wx;
    out[idx] = top * (1.0f - wy) + bot * wy;
}

extern "C" void kernel_launch(void* const* d_in, const int* in_sizes, int n_in,
                              void* d_out, int out_size, void* d_ws, size_t ws_size,
                              hipStream_t stream) {
    // input order: imgs, intrs, c2ws, near_fars, density_volume, stage_idx
    const float* intrs = (const float*)d_in[1];
    const float* c2ws  = (const float*)d_in[2];
    const float* nf    = (const float*)d_in[3];
    const float* vol   = (const float*)d_in[4];
    float* out = (float*)d_out;

    float* depth_low = (float*)d_ws;                    // 3*65536 floats
    float* partials  = depth_low + NVIEW * NPIX;        // 3*512*3 floats

    raymarch_kernel<<<NVIEW * BLOCKS_PER_VIEW, BLK, 0, stream>>>(
        intrs, c2ws, nf, vol, depth_low, partials);
    reduce_occ_kernel<<<NVIEW, 256, 0, stream>>>(
        partials, out + NVIEW * IMGH * IMGW);
    upsample_kernel<<<(NVIEW * IMGH * IMGW) / BLK, BLK, 0, stream>>>(
        depth_low, out);
}

// Round 5
// 51.394 us; speedup vs baseline: 1.1894x; 1.1894x over previous
//
#include <hip/hip_runtime.h>
#include <hip/hip_fp16.h>
#include <math.h>

#define NVIEW 3
#define HLOW 256
#define WLOW 256
#define NPIX (HLOW * WLOW)
#define NS 64
#define VOLN 128
#define IMGH 512
#define IMGW 512
#define BLK 256
#define BLOCKS_PER_VIEW (NPIX / BLK)   // 256
#define NVOX (VOLN * VOLN * VOLN)      // 2097152
#define UPS_BLOCKS ((NVIEW * IMGH * IMGW) / BLK) // 3072

// ---------------- per-ray setup (shared) ----------------
struct Ray {
    float gx0, gxs, gy0, gys, gz0, gzs;  // grid coords affine in z
    float zlo, zhi;                      // outside-unit-sphere z interval
    float z0, zstep, ncz;
};

__device__ __forceinline__ Ray ray_setup(
    int view, int row, int col,
    const float* __restrict__ intrs, const float* __restrict__ c2ws,
    const float* __restrict__ nf)
{
    const float px = 511.0f * (float)col * (1.0f / 255.0f);
    const float py = 511.0f * (float)row * (1.0f / 255.0f);

    const float* K = intrs + view * 9;
    const float a = K[0], b = K[1], c = K[2];
    const float d = K[3], e = K[4], f = K[5];
    const float g = K[6], h = K[7], i9 = K[8];
    const float det = a * (e * i9 - f * h) - b * (d * i9 - f * g) + c * (d * h - e * g);
    const float id = 1.0f / det;
    const float m00 = (e * i9 - f * h) * id, m01 = -(b * i9 - c * h) * id, m02 = (b * f - c * e) * id;
    const float m10 = -(d * i9 - f * g) * id, m11 = (a * i9 - c * g) * id, m12 = -(a * f - c * d) * id;
    const float m20 = (d * h - e * g) * id, m21 = -(a * h - b * g) * id, m22 = (a * e - b * d) * id;

    const float cx = m00 * px + m01 * py + m02;
    const float cy = m10 * px + m11 * py + m12;
    const float cz = m20 * px + m21 * py + m22;
    const float inr = rsqrtf(cx * cx + cy * cy + cz * cz);
    const float ncx = cx * inr, ncy = cy * inr, ncz = cz * inr;

    const float* M = c2ws + view * 16;
    const float dx = M[0] * ncx + M[1] * ncy + M[2] * ncz;
    const float dy = M[4] * ncx + M[5] * ncy + M[6] * ncz;
    const float dz = M[8] * ncx + M[9] * ncy + M[10] * ncz;
    const float tx = M[3], ty = M[7], tz = M[11];

    Ray r;
    r.gx0 = (tx + 1.0f) * 63.5f; r.gxs = dx * 63.5f;
    r.gy0 = (ty + 1.0f) * 63.5f; r.gys = dy * 63.5f;
    r.gz0 = (tz + 1.0f) * 63.5f; r.gzs = dz * 63.5f;

    const float bq = tx * dx + ty * dy + tz * dz;
    const float cq = tx * tx + ty * ty + tz * tz;
    const float disc = bq * bq - (cq - 1.0f);
    if (disc >= 0.0f) {
        const float rt = sqrtf(disc);
        r.zlo = -bq - rt;
        r.zhi = -bq + rt;
    } else {
        r.zlo = 3.4e38f;
        r.zhi = 0.0f;
    }

    r.z0 = nf[view * 2 + 0];
    r.zstep = (nf[view * 2 + 1] - r.z0) * (1.0f / 63.0f);
    r.ncz = ncz;
    return r;
}

// ---------------- corner-fetch variants ----------------
struct C8 { float2 p00, p01, p10, p11; }; // p{z}{y} = (x0, x1)

__device__ __forceinline__ C8 fetch_quad(const void* Fv, unsigned off) {
    const uint4 q = reinterpret_cast<const uint4*>(Fv)[off];
    union { unsigned u; __half2 h; } a;
    C8 c;
    a.u = q.x; c.p00 = __half22float2(a.h);
    a.u = q.y; c.p01 = __half22float2(a.h);
    a.u = q.z; c.p10 = __half22float2(a.h);
    a.u = q.w; c.p11 = __half22float2(a.h);
    return c;
}

__device__ __forceinline__ C8 fetch_pair(const void* Fv, unsigned off) {
    const uint2 q0 = reinterpret_cast<const uint2*>(Fv)[off];
    const uint2 q1 = reinterpret_cast<const uint2*>(Fv)[off + VOLN * VOLN];
    union { unsigned u; __half2 h; } a;
    C8 c;
    a.u = q0.x; c.p00 = __half22float2(a.h);
    a.u = q0.y; c.p01 = __half22float2(a.h);
    a.u = q1.x; c.p10 = __half22float2(a.h);
    a.u = q1.y; c.p11 = __half22float2(a.h);
    return c;
}

__device__ __forceinline__ C8 fetch_f32(const void* Fv, unsigned off) {
    const float* p0 = reinterpret_cast<const float*>(Fv) + off;
    C8 c;
    c.p00 = *reinterpret_cast<const float2*>(p0);
    c.p01 = *reinterpret_cast<const float2*>(p0 + VOLN);
    c.p10 = *reinterpret_cast<const float2*>(p0 + VOLN * VOLN);
    c.p11 = *reinterpret_cast<const float2*>(p0 + VOLN * VOLN + VOLN);
    return c;
}

// ---------------- build kernels (per-launch, deterministic) ----------------
// F[z][y][x] = f16 x8: all 8 corners of cell (x..x+1, y..y+1, z..z+1), clamped.
__global__ __launch_bounds__(BLK) void build_quad_kernel(
    const float* __restrict__ vol, uint4* __restrict__ F)
{
    const int id = blockIdx.x * BLK + threadIdx.x;
    const int x = id & 127;
    const int y = (id >> 7) & 127;
    const int z = id >> 14;
    const int xp = min(x + 1, 127);
    const int yp = min(y + 1, 127);
    const int zp = min(z + 1, 127);
    const float* r00 = vol + (z * VOLN + y) * VOLN;
    const float* r01 = vol + (z * VOLN + yp) * VOLN;
    const float* r10 = vol + (zp * VOLN + y) * VOLN;
    const float* r11 = vol + (zp * VOLN + yp) * VOLN;
    const __half2 h0 = __floats2half2_rn(r00[x], r00[xp]);
    const __half2 h1 = __floats2half2_rn(r01[x], r01[xp]);
    const __half2 h2 = __floats2half2_rn(r10[x], r10[xp]);
    const __half2 h3 = __floats2half2_rn(r11[x], r11[xp]);
    uint4 o;
    o.x = *reinterpret_cast<const unsigned*>(&h0);
    o.y = *reinterpret_cast<const unsigned*>(&h1);
    o.z = *reinterpret_cast<const unsigned*>(&h2);
    o.w = *reinterpret_cast<const unsigned*>(&h3);
    F[id] = o;
}

// P[z][y][x] = f16 x4: the 2x2 (y,x) corners at this z (z handled by 2 loads).
__global__ __launch_bounds__(BLK) void build_pair_kernel(
    const float* __restrict__ vol, uint2* __restrict__ P)
{
    const int id = blockIdx.x * BLK + threadIdx.x;
    const int x = id & 127;
    const int y = (id >> 7) & 127;
    const int z = id >> 14;
    const int xp = min(x + 1, 127);
    const int yp = min(y + 1, 127);
    const float* r0 = vol + (z * VOLN + y) * VOLN;
    const float* r1 = vol + (z * VOLN + yp) * VOLN;
    const __half2 h0 = __floats2half2_rn(r0[x], r0[xp]);
    const __half2 h1 = __floats2half2_rn(r1[x], r1[xp]);
    uint2 o;
    o.x = *reinterpret_cast<const unsigned*>(&h0);
    o.y = *reinterpret_cast<const unsigned*>(&h1);
    P[id] = o;
}

// ---------------- raymarch (MODE: 0=quad f16, 1=pair f16, 2=f32 direct) ----
template <int MODE>
__global__ __launch_bounds__(BLK) void raymarch_kernel(
    const float* __restrict__ intrs, const float* __restrict__ c2ws,
    const float* __restrict__ nf, const void* __restrict__ Fv,
    float* __restrict__ depth_low, float* __restrict__ partials)
{
    const int view = blockIdx.x >> 8;
    const int tb   = blockIdx.x & 255;
    const int t    = threadIdx.x;
    const int wave = t >> 6, lane = t & 63;
    // block = 16x16 pixel tile; wave = 8x8 sub-tile (shrinks per-gather footprint)
    const int row = ((tb >> 4) << 4) + ((wave >> 1) << 3) + (lane >> 3);
    const int col = ((tb & 15) << 4) + ((wave & 1) << 3) + (lane & 7);

    const Ray r = ray_setup(view, row, col, intrs, c2ws, nf);

    float lsum = 0.0f, zacc = 0.0f;
    float d6 = 0.0f, dout = 0.0f, cnt = 0.0f;

    #pragma unroll 8
    for (int s = 0; s < NS; ++s) {
        const float z = fmaf(r.zstep, (float)s, r.z0);
        float gx = fmaf(r.gxs, z, r.gx0);
        float gy = fmaf(r.gys, z, r.gy0);
        float gz = fmaf(r.gzs, z, r.gz0);
        gx = fminf(fmaxf(gx, 0.0f), 127.0f);
        gy = fminf(fmaxf(gy, 0.0f), 127.0f);
        gz = fminf(fmaxf(gz, 0.0f), 127.0f);

        const int xb = min((int)gx, VOLN - 2);
        const int yb = min((int)gy, VOLN - 2);
        const int zb = min((int)gz, VOLN - 2);
        const float fx = gx - (float)xb;
        const float fy = gy - (float)yb;
        const float fz = gz - (float)zb;

        const unsigned off = ((unsigned)zb << 14) + ((unsigned)yb << 7) + (unsigned)xb;
        const C8 cc = (MODE == 0) ? fetch_quad(Fv, off)
                    : (MODE == 1) ? fetch_pair(Fv, off)
                                  : fetch_f32(Fv, off);

        const float c00 = fmaf(fx, cc.p00.y - cc.p00.x, cc.p00.x);
        const float c01 = fmaf(fx, cc.p01.y - cc.p01.x, cc.p01.x);
        const float c10 = fmaf(fx, cc.p10.y - cc.p10.x, cc.p10.x);
        const float c11 = fmaf(fx, cc.p11.y - cc.p11.x, cc.p11.x);
        const float c0 = fmaf(fy, c01 - c00, c00);
        const float c1 = fmaf(fy, c11 - c10, c10);
        const float dens = fmaf(fz, c1 - c0, c0);

        const float w = __expf(dens);
        lsum += w;
        zacc = fmaf(z, w, zacc);

        if (s < 6) d6 += dens;
        const bool o = (z < r.zlo) || (z > r.zhi);
        dout += o ? dens : 0.0f;
        cnt  += o ? 1.0f : 0.0f;
    }

    depth_low[view * NPIX + row * WLOW + col] = (zacc / lsum) * r.ncz;

    __shared__ float s0[BLK], s1[BLK], s2[BLK];
    s0[t] = d6; s1[t] = dout; s2[t] = cnt;
    __syncthreads();
    for (int off = BLK / 2; off > 0; off >>= 1) {
        if (t < off) {
            s0[t] += s0[t + off];
            s1[t] += s1[t + off];
            s2[t] += s2[t + off];
        }
        __syncthreads();
    }
    if (t == 0) {
        partials[blockIdx.x * 3 + 0] = s0[0];
        partials[blockIdx.x * 3 + 1] = s1[0];
        partials[blockIdx.x * 3 + 2] = s2[0];
    }
}

// ---------------- fused epilogue: upsample (blocks 0..3071) + occ reduce ----
__global__ __launch_bounds__(BLK) void epilogue_kernel(
    const float* __restrict__ low, const float* __restrict__ partials,
    float* __restrict__ out)
{
    if (blockIdx.x >= UPS_BLOCKS) {
        const int view = blockIdx.x - UPS_BLOCKS;
        const int t = threadIdx.x;
        __shared__ float s0[BLK], s1[BLK], s2[BLK];
        const int bi = view * BLOCKS_PER_VIEW + t; // BLOCKS_PER_VIEW == BLK
        s0[t] = partials[bi * 3 + 0];
        s1[t] = partials[bi * 3 + 1];
        s2[t] = partials[bi * 3 + 2];
        __syncthreads();
        for (int off = BLK / 2; off > 0; off >>= 1) {
            if (t < off) {
                s0[t] += s0[t + off];
                s1[t] += s1[t + off];
                s2[t] += s2[t + off];
            }
            __syncthreads();
        }
        if (t == 0) {
            out[NVIEW * IMGH * IMGW + view] =
                s0[0] * (1.0f / (float)(NPIX * 6)) + s1[0] / (s2[0] + 1e-10f);
        }
        return;
    }

    const int idx = blockIdx.x * BLK + threadIdx.x;
    const int view = idx / (IMGH * IMGW);
    const int rem = idx - view * (IMGH * IMGW);
    const int rr = rem >> 9;
    const int cc = rem & 511;

    const float sy = (float)rr * 0.5f - 0.25f;
    const float sx = (float)cc * 0.5f - 0.25f;
    const float y0f = floorf(sy), x0f = floorf(sx);
    const float wy = sy - y0f, wx = sx - x0f;
    const int y0 = (int)y0f, x0 = (int)x0f;
    const int y0c = max(y0, 0), y1c = min(y0 + 1, HLOW - 1);
    const int x0c = max(x0, 0), x1c = min(x0 + 1, WLOW - 1);

    const float* src = low + view * NPIX;
    const float v00 = src[y0c * WLOW + x0c];
    const float v01 = src[y0c * WLOW + x1c];
    const float v10 = src[y1c * WLOW + x0c];
    const float v11 = src[y1c * WLOW + x1c];

    const float top = v00 * (1.0f - wx) + v01 * wx;
    const float bot = v10 * (1.0f - wx) + v11 * wx;
    out[idx] = top * (1.0f - wy) + bot * wy;
}

extern "C" void kernel_launch(void* const* d_in, const int* in_sizes, int n_in,
                              void* d_out, int out_size, void* d_ws, size_t ws_size,
                              hipStream_t stream) {
    // input order: imgs, intrs, c2ws, near_fars, density_volume, stage_idx
    const float* intrs = (const float*)d_in[1];
    const float* c2ws  = (const float*)d_in[2];
    const float* nf    = (const float*)d_in[3];
    const float* vol   = (const float*)d_in[4];
    float* out = (float*)d_out;

    const size_t quad_bytes  = (size_t)NVOX * 16;
    const size_t pair_bytes  = (size_t)NVOX * 8;
    const size_t depth_bytes = (size_t)NVIEW * NPIX * 4;
    const size_t part_bytes  = (size_t)NVIEW * BLOCKS_PER_VIEW * 3 * 4;
    char* ws = (char*)d_ws;

    float* depth_low;
    float* partials;

    if (ws_size >= quad_bytes + depth_bytes + part_bytes) {
        uint4* F = (uint4*)ws;
        depth_low = (float*)(ws + quad_bytes);
        partials  = depth_low + NVIEW * NPIX;
        build_quad_kernel<<<NVOX / BLK, BLK, 0, stream>>>(vol, F);
        raymarch_kernel<0><<<NVIEW * BLOCKS_PER_VIEW, BLK, 0, stream>>>(
            intrs, c2ws, nf, (const void*)F, depth_low, partials);
    } else if (ws_size >= pair_bytes + depth_bytes + part_bytes) {
        uint2* P = (uint2*)ws;
        depth_low = (float*)(ws + pair_bytes);
        partials  = depth_low + NVIEW * NPIX;
        build_pair_kernel<<<NVOX / BLK, BLK, 0, stream>>>(vol, P);
        raymarch_kernel<1><<<NVIEW * BLOCKS_PER_VIEW, BLK, 0, stream>>>(
            intrs, c2ws, nf, (const void*)P, depth_low, partials);
    } else {
        depth_low = (float*)ws;
        partials  = depth_low + NVIEW * NPIX;
        raymarch_kernel<2><<<NVIEW * BLOCKS_PER_VIEW, BLK, 0, stream>>>(
            intrs, c2ws, nf, (const void*)vol, depth_low, partials);
    }

    epilogue_kernel<<<UPS_BLOCKS + NVIEW, BLK, 0, stream>>>(depth_low, partials, out);
}